// Round 12
// baseline (68.103 us; speedup 1.0000x reference)
//
#include <hip/hip_runtime.h>

#define IMH 384
#define IMW 384
#define OH 378
#define OW 378
#define NB 64
#define SROWS 18
#define INROWS 24          // computed rows per strip = 12 pairs exactly
#define NSTRIP 21          // 21*18 = 378 exactly
#define BLOCK 256          // 4 waves = 16 DPP groups of 16 lanes
#define GSTRIDE 26         // output cols per group (13 lanes x 2 cols)
#define NPAIR 12           // staged row-pairs (24 rows, no pad row)
#define SLOTF 384          // floats per row slot: EXACT row, no pad
#define NBLK (NSTRIP * NB) // 1344 blocks = partial count

// Round 21: R20 proved barriers+ds_read ~= 0.3us total -> scheduling family
// exhausted at 27.9us (VALU ~8, mem-bytes ~8). Three additive levers:
//  1. Sum-domain SSIM: N1,N2,D1,D2 straight from S0..S4 with c1s=(0.49L)^2,
//     c2s=(1.47L)^2 (49^4 cancels in the ratio). 19 -> 12 pk instrs per
//     output row (-8% VALU).
//  2. Compact staging: waves stage floats [0,256) and [128,384) (overlap
//     written twice, byte-identical -> benign). No slot pad: ring 32->24KB,
//     6 blocks/CU cap; SROWS 18 -> 1344 blocks, ~21 waves/CU (+17% hiding,
//     +3.7% bytes). INROWS 24 = 12 pairs exactly -> no clamped pad row.
//  3. Fused finalize: block stores partial, threadfence, ticket atomic
//     (4B memset per replay); last block (old==1343) atomic-reads partials
//     and writes out. Distinct addresses -> no R11 pileup. Saves dispatch.
// PRED: LDS ~24.6KB, VGPR 70-90, dur 27.9 -> 23-25.5us. Flat >=27 ->
// R22 probes I-cache (rolled 7-pair loop with shift-register history).

template <int CTRL>
__device__ __forceinline__ float dpp_sh(float v) {
    return __int_as_float(__builtin_amdgcn_update_dpp(
        0, __float_as_int(v), CTRL, 0xf, 0xf, true));
}

__device__ __forceinline__ float2 f2add(float2 a, float2 b) { return make_float2(a.x + b.x, a.y + b.y); }
__device__ __forceinline__ float2 f2sub(float2 a, float2 b) { return make_float2(a.x - b.x, a.y - b.y); }
__device__ __forceinline__ float2 f2mul(float2 a, float2 b) { return make_float2(a.x * b.x, a.y * b.y); }
__device__ __forceinline__ float2 f2fma(float2 a, float2 b, float2 c) {
    return make_float2(fmaf(a.x, b.x, c.x), fmaf(a.y, b.y, c.y));
}
__device__ __forceinline__ float2 f2fnma(float2 a, float2 b, float2 c) {  // c - a*b
    return make_float2(fmaf(-a.x, b.x, c.x), fmaf(-a.y, b.y, c.y));
}
__device__ __forceinline__ float2 f2fms(float2 a, float s, float2 c) {    // a*s - c
    return make_float2(fmaf(a.x, s, -c.x), fmaf(a.y, s, -c.y));
}
__device__ __forceinline__ float2 f2s(float s) { return make_float2(s, s); }

// async global->LDS DMA, 16B per lane; dest = wave-uniform base + lane*16B
__device__ __forceinline__ void stage16(const float* g, float* l) {
    __builtin_amdgcn_global_load_lds(
        (const __attribute__((address_space(1))) uint32_t*)(g),
        (__attribute__((address_space(3))) uint32_t*)(l),
        16, 0, 0);
}

#define WAITV(n) asm volatile("s_waitcnt vmcnt(" #n ")" ::: "memory")
#define RAWBAR() asm volatile("s_barrier" ::: "memory")

__global__ __launch_bounds__(BLOCK)
__attribute__((amdgpu_waves_per_eu(5, 8)))
void ssim_kernel(
    const float* __restrict__ X, const float* __restrict__ Y,
    const float* __restrict__ data_range, float* __restrict__ partials,
    float* __restrict__ out)
{
    const int tid   = threadIdx.x;
    const int g     = tid >> 4;               // DPP group 0..15
    const int j     = tid & 15;               // lane within group
    const int strip = blockIdx.x;
    const int b     = blockIdx.y;
    const int y0    = strip * SROWS;          // <= 360; +23 = 383 in range

    // pair-slot ring: [pairslot][row-in-pair][384 floats]; 12 KB per tensor
    __shared__ float sX[4][2][SLOTF];
    __shared__ float sY[4][2][SLOTF];
    __shared__ int lastflag;

    // ---- staging role: wv0=X[0,256) wv1=X[128,384) wv2/3 same for Y ----
    // Overlap floats [128,256) written by two waves with IDENTICAL data.
    const int wv   = tid >> 6;
    const int ln   = tid & 63;
    const bool isX = (wv < 2);
    const int half = wv & 1;
    const int foff = half * 128 + ln * 4;     // 0..252 or 128..380, no clamp
    const float* __restrict__ gstg =
        (isX ? X : Y) + b * (IMH * IMW) + y0 * IMW + foff;
    float* const lbase = (isX ? &sX[0][0][0] : &sY[0][0][0]) + half * 128;

    // compute-side column mapping (unchanged)
    const int ce  = g * GSTRIDE + 2 * j;      // lane's even column (global)
    const int cin = min(ce, IMW - 2);         // clamped, even -> 8B aligned
    const float2 vmask = make_float2(
        ((j <= 12) && (ce     < OW)) ? 1.f : 0.f,
        ((j <= 12) && (ce + 1 < OW)) ? 1.f : 0.f);

    // sum-domain constants: S = (N1*N2)/(D1*D2), all scaled by 49^4
    const float L   = data_range[b];
    const float c1s = (0.49f * L) * (0.49f * L);      // 49^2 * C1
    const float c2s = (1.47f * L) * (1.47f * L);      // 49^2 * C2
    const float k1  = 49.0f / 48.0f;                  // covn
    const float k2  = 49.0f / 24.0f;                  // 2*covn
    asm volatile("" :: "v"(c1s), "v"(c2s));
    __builtin_amdgcn_sched_barrier(0);

    // ---- prologue: DMA pairs 0..3 (8 instrs/wave), wave-linear dests ----
    #pragma unroll
    for (int q = 0; q < 4; ++q) {
        stage16(gstg + (2 * q) * IMW,     lbase + (2 * q + 0) * SLOTF);
        stage16(gstg + (2 * q + 1) * IMW, lbase + (2 * q + 1) * SLOTF);
    }
    WAITV(6);                                 // own pair-0 DMAs complete
    RAWBAR();                                 // all waves' pair 0 complete
    float2 cx0 = *(const float2*)&sX[0][0][cin];
    float2 cx1 = *(const float2*)&sX[0][1][cin];
    float2 cy0 = *(const float2*)&sY[0][0][cin];
    float2 cy1 = *(const float2*)&sY[0][1][cin];

    float2 xh[7], yh[7];
    #pragma unroll
    for (int k = 0; k < 7; ++k) { xh[k] = f2s(0.f); yh[k] = f2s(0.f); }
    float2 V0 = f2s(0.f), V1 = f2s(0.f), V2 = f2s(0.f),
           V3 = f2s(0.f), V4 = f2s(0.f);
    float2 ls2 = f2s(0.f);

    auto rowcompute = [&](int r, float2 x, float2 y) {
        const int ks = r % 7;                          // static after unroll
        const float2 xo = xh[ks], yo = yh[ks];
        V0 = f2add(V0, f2sub(x, xo));
        V1 = f2add(V1, f2sub(y, yo));
        V2 = f2fma(x, x, V2);  V2 = f2fnma(xo, xo, V2);
        V3 = f2fma(x, y, V3);  V3 = f2fnma(xo, yo, V3);
        V4 = f2fma(y, y, V4);  V4 = f2fnma(yo, yo, V4);
        xh[ks] = x; yh[ks] = y;

        if (r >= 6) {   // output row o = y0+r-6 < OH by tiling
            const float2 Vv[5] = {V0, V1, V2, V3, V4};
            float Se[5], So[5];
            #pragma unroll
            for (int q = 0; q < 5; ++q) {
                const float e  = Vv[q].x;
                const float o  = Vv[q].y;
                const float pp = e + o;
                float B = pp + dpp_sh<0x101>(pp);      // pp(l)+pp(l+1)
                float C = B + dpp_sh<0x102>(B);        // pp(l..l+3)
                Se[q] = C - dpp_sh<0x103>(o);          // cols 2l..2l+6
                So[q] = C - e;                         // cols 2l+1..2l+7
            }
            const float2 S0 = make_float2(Se[0], So[0]);
            const float2 S1 = make_float2(Se[1], So[1]);
            const float2 S2 = make_float2(Se[2], So[2]);
            const float2 S3 = make_float2(Se[3], So[3]);
            const float2 S4 = make_float2(Se[4], So[4]);

            // sum-domain SSIM (scale 49^4 cancels in the ratio)
            float2 P  = f2mul(S0, S1);
            float2 q1 = f2mul(S1, S1);
            float2 QQ = f2fma(S0, S0, q1);
            float2 N1 = f2fma(f2s(2.f), P, f2s(c1s));
            float2 D1 = f2add(QQ, f2s(c1s));
            float2 w  = f2fms(S3, 49.0f, P);           // 49*S3 - S0*S1
            float2 N2 = f2fma(f2s(k2), w, f2s(c2s));
            float2 t  = f2add(S2, S4);
            float2 u  = f2fms(t, 49.0f, QQ);           // 49*(S2+S4) - QQ
            float2 D2 = f2fma(f2s(k1), u, f2s(c2s));
            float2 num = f2mul(N1, N2);
            float2 den = f2mul(D1, D2);
            const float rdd = __builtin_amdgcn_rcpf(den.x * den.y);
            float2 s2 = make_float2(num.x * den.y * rdd,
                                    num.y * den.x * rdd);
            ls2 = f2fma(s2, vmask, ls2);
        }
    };

    static_assert(INROWS == 24 && NPAIR == 12, "ladder");

    #pragma unroll
    for (int p = 1; p < NPAIR; ++p) {
        // wait own pair-p DMAs; steady outstanding before wait = 6
        if      (p <= 9)  WAITV(4);
        else if (p == 10) WAITV(2);
        else              WAITV(0);
        RAWBAR();                             // all waves' pair p complete

        // read pair p into next-regs (hides under pair p-1 compute)
        const int sl = p & 3;
        float2 nx0 = *(const float2*)&sX[sl][0][cin];
        float2 nx1 = *(const float2*)&sX[sl][1][cin];
        float2 ny0 = *(const float2*)&sY[sl][0][cin];
        float2 ny1 = *(const float2*)&sY[sl][1][cin];

        // compute pair p-1 from cur-regs
        rowcompute(2 * (p - 1),     cx0, cy0);
        rowcompute(2 * (p - 1) + 1, cx1, cy1);

        // issue DMA pair p+3 into slot (p+3)&3 (== (p-1)&3): that slot's
        // ds_reads completed last iter (lgkm drained before use); the DMA's
        // LDS write lands ~HBM-latency later -> race-free.
        if (p + 3 < NPAIR) {
            const int q = p + 3;
            stage16(gstg + (2 * q) * IMW,     lbase + ((q & 3) * 2 + 0) * SLOTF);
            stage16(gstg + (2 * q + 1) * IMW, lbase + ((q & 3) * 2 + 1) * SLOTF);
        }

        cx0 = nx0; cx1 = nx1; cy0 = ny0; cy1 = ny1;
    }

    // epilogue: pair 11 = rows 22, 23 (both real)
    rowcompute(22, cx0, cy0);
    rowcompute(23, cx1, cy1);

    // ---- block reduce -> partial store -> ticket; last block finalizes ----
    float lsum = ls2.x + ls2.y;
    #pragma unroll
    for (int off = 32; off > 0; off >>= 1)
        lsum += __shfl_down(lsum, off, 64);
    __syncthreads();                          // loop fully done, LDS free
    if ((tid & 63) == 0) sX[0][0][tid >> 6] = lsum;
    __syncthreads();
    if (tid == 0) {
        const float bs = sX[0][0][0] + sX[0][0][1]
                       + sX[0][0][2] + sX[0][0][3];
        partials[b * NSTRIP + strip] = bs;
        __threadfence();                      // release partial before ticket
        const unsigned old =
            atomicAdd((unsigned*)(partials + NBLK), 1u);
        lastflag = (old == NBLK - 1) ? 1 : 0;
    }
    __syncthreads();
    if (lastflag && tid < 64) {
        __threadfence();                      // acquire side
        float v = 0.f;
        #pragma unroll
        for (int k = 0; k < NBLK / 64; ++k)   // 21 reads per lane
            v += atomicAdd(partials + tid + 64 * k, 0.0f);
        #pragma unroll
        for (int off = 32; off > 0; off >>= 1)
            v += __shfl_down(v, off, 64);
        if (tid == 0)
            out[0] = 1.0f - v * (1.0f / (float)(NB * OH * OW));
    }
}

extern "C" void kernel_launch(void* const* d_in, const int* in_sizes, int n_in,
                              void* d_out, int out_size, void* d_ws, size_t ws_size,
                              hipStream_t stream) {
    const float* X  = (const float*)d_in[0];
    const float* Y  = (const float*)d_in[1];
    const float* dr = (const float*)d_in[2];
    float* out = (float*)d_out;
    float* partials = (float*)d_ws;           // NBLK floats + 1 ticket word

    // zero ONLY the 4-byte ticket each replay; partials are plain-stored
    hipMemsetAsync((char*)d_ws + NBLK * sizeof(float), 0, sizeof(unsigned),
                   stream);

    dim3 grid(NSTRIP, NB);      // 21 x 64 = 1344 blocks
    dim3 block(BLOCK);          // 256 threads = 4 waves
    ssim_kernel<<<grid, block, 0, stream>>>(X, Y, dr, partials, out);
}

// Round 13
// 26.095 us; speedup vs baseline: 2.6098x; 2.6098x over previous
//
#include <hip/hip_runtime.h>

#define IMH 384
#define IMW 384
#define OH 378
#define OW 378
#define NB 64
#define SROWS 21
#define INROWS 27          // computed rows per strip (27 = 21 + 6)
#define NSTRIP 18          // 18*21 = 378 exactly
#define BLOCK 256          // 4 waves = 16 DPP groups of 16 lanes
#define GSTRIDE 26         // output cols per group (13 lanes x 2 cols)
#define NPAIR 14           // staged row-pairs (28 rows; row 27 = clamped pad)
#define SLOTF 512          // floats per row: 384 data + 128 pad (2048 B)

// Round 22: R21 regressed 27.9 -> 68us and the counters convict the
// allocator, not the levers: VGPR=40 (the R8/R11 remat pathology) under
// waves_per_eu(5,8) — allocator chased the 8-wave tier (64-reg budget),
// rematerialized the pipeline regs as use-site LDS re-reads -> VALUBusy
// 15%, everything serial. Fix this round, de-confounded:
//  1. REVERT to the R20 shell verbatim (27.9us proven): SROWS 21, 2KB
//     slots, separate finalize, same wait ladder.
//  2. waves_per_eu(6,6): max=6 forbids the 64-reg tier; budget ~85 for a
//     ~60 live set -> no remat incentive (R10 precedent).
//  3. Sum-domain SSIM (R21 lever 1, absmax-0-verified): N1/N2/D1/D2 from
//     S0..S4 with c1s=(0.49L)^2, c2s=(1.47L)^2, k1=49/48, k2=49/24; the
//     49^4 scale cancels in the ratio. 19 -> 12 pk instrs per output row.
// PRED: VGPR 70-90 (DIAGNOSTIC: <=48 falsifies the (6,6) fix), LDS 32768,
// dur 25.5-27us. VGPR healthy but >29us falsifies the algebra gain.

template <int CTRL>
__device__ __forceinline__ float dpp_sh(float v) {
    return __int_as_float(__builtin_amdgcn_update_dpp(
        0, __float_as_int(v), CTRL, 0xf, 0xf, true));
}

__device__ __forceinline__ float2 f2add(float2 a, float2 b) { return make_float2(a.x + b.x, a.y + b.y); }
__device__ __forceinline__ float2 f2sub(float2 a, float2 b) { return make_float2(a.x - b.x, a.y - b.y); }
__device__ __forceinline__ float2 f2mul(float2 a, float2 b) { return make_float2(a.x * b.x, a.y * b.y); }
__device__ __forceinline__ float2 f2fma(float2 a, float2 b, float2 c) {
    return make_float2(fmaf(a.x, b.x, c.x), fmaf(a.y, b.y, c.y));
}
__device__ __forceinline__ float2 f2fnma(float2 a, float2 b, float2 c) {  // c - a*b
    return make_float2(fmaf(-a.x, b.x, c.x), fmaf(-a.y, b.y, c.y));
}
__device__ __forceinline__ float2 f2fms(float2 a, float s, float2 c) {    // a*s - c
    return make_float2(fmaf(a.x, s, -c.x), fmaf(a.y, s, -c.y));
}
__device__ __forceinline__ float2 f2s(float s) { return make_float2(s, s); }

// async global->LDS DMA, 16B per lane; dest = wave-uniform base + lane*16B
__device__ __forceinline__ void stage16(const float* g, float* l) {
    __builtin_amdgcn_global_load_lds(
        (const __attribute__((address_space(1))) uint32_t*)(g),
        (__attribute__((address_space(3))) uint32_t*)(l),
        16, 0, 0);
}

#define WAITV(n) asm volatile("s_waitcnt vmcnt(" #n ")" ::: "memory")
#define RAWBAR() asm volatile("s_barrier" ::: "memory")

__global__ __launch_bounds__(BLOCK)
__attribute__((amdgpu_waves_per_eu(6, 6)))
void ssim_kernel(
    const float* __restrict__ X, const float* __restrict__ Y,
    const float* __restrict__ data_range, float* __restrict__ partials)
{
    const int tid   = threadIdx.x;
    const int g     = tid >> 4;               // DPP group 0..15
    const int j     = tid & 15;               // lane within group
    const int strip = blockIdx.x;
    const int b     = blockIdx.y;
    const int y0    = strip * SROWS;          // <= 357

    // pair-slot ring: [pairslot][row-in-pair][floats]; 16 KB per tensor
    __shared__ float sX[4][2][SLOTF];
    __shared__ float sY[4][2][SLOTF];

    // ---- staging role (R17/R20 shell): wv0=X-lo wv1=X-hi wv2=Y-lo wv3=Y-hi
    const int wv   = tid >> 6;
    const int ln   = tid & 63;
    const bool isX = (wv < 2);
    const int half = wv & 1;                  // 0: floats 0..255, 1: 256..511
    const int foff = half * 256 + ln * 4;     // float col of this lane's 16B
    const int fcl  = min(foff, IMW - 4);      // pad lanes re-read last 16B
    const float* __restrict__ gstg =
        (isX ? X : Y) + b * (IMH * IMW) + y0 * IMW + fcl;
    const float* __restrict__ gstg27 =        // row 27, clamped (strip 17)
        (isX ? X : Y) + b * (IMH * IMW) + min(y0 + 27, IMH - 1) * IMW + fcl;
    float* const lbase = (isX ? &sX[0][0][0] : &sY[0][0][0]) + foff;

    // compute-side column mapping (unchanged)
    const int ce  = g * GSTRIDE + 2 * j;      // lane's even column (global)
    const int cin = min(ce, IMW - 2);         // clamped, even -> 8B aligned
    const float2 vmask = make_float2(
        ((j <= 12) && (ce     < OW)) ? 1.f : 0.f,
        ((j <= 12) && (ce + 1 < OW)) ? 1.f : 0.f);

    // sum-domain constants (scale 49^4 cancels in the SSIM ratio)
    const float L   = data_range[b];
    const float c1s = (0.49f * L) * (0.49f * L);      // 49^2 * C1
    const float c2s = (1.47f * L) * (1.47f * L);      // 49^2 * C2
    const float k1  = 49.0f / 48.0f;                  // covn
    const float k2  = 49.0f / 24.0f;                  // 2*covn
    asm volatile("" :: "v"(c1s), "v"(c2s));
    __builtin_amdgcn_sched_barrier(0);

    // ---- prologue: DMA pairs 0..3 (8 instrs/wave) ----
    #pragma unroll
    for (int q = 0; q < 4; ++q) {
        stage16(gstg + (2 * q) * IMW,     lbase + (2 * q + 0) * SLOTF);
        stage16(gstg + (2 * q + 1) * IMW, lbase + (2 * q + 1) * SLOTF);
    }
    WAITV(6);                                 // pair 0 complete (own)
    RAWBAR();                                 // all waves' pair 0 complete
    float2 cx0 = *(const float2*)&sX[0][0][cin];
    float2 cx1 = *(const float2*)&sX[0][1][cin];
    float2 cy0 = *(const float2*)&sY[0][0][cin];
    float2 cy1 = *(const float2*)&sY[0][1][cin];

    float2 xh[7], yh[7];
    #pragma unroll
    for (int k = 0; k < 7; ++k) { xh[k] = f2s(0.f); yh[k] = f2s(0.f); }
    float2 V0 = f2s(0.f), V1 = f2s(0.f), V2 = f2s(0.f),
           V3 = f2s(0.f), V4 = f2s(0.f);
    float2 ls2 = f2s(0.f);

    auto rowcompute = [&](int r, float2 x, float2 y) {
        const int ks = r % 7;                          // static after unroll
        const float2 xo = xh[ks], yo = yh[ks];
        V0 = f2add(V0, f2sub(x, xo));
        V1 = f2add(V1, f2sub(y, yo));
        V2 = f2fma(x, x, V2);  V2 = f2fnma(xo, xo, V2);
        V3 = f2fma(x, y, V3);  V3 = f2fnma(xo, yo, V3);
        V4 = f2fma(y, y, V4);  V4 = f2fnma(yo, yo, V4);
        xh[ks] = x; yh[ks] = y;

        if (r >= 6) {   // output row o = y0+r-6 < OH by tiling
            const float2 Vv[5] = {V0, V1, V2, V3, V4};
            float Se[5], So[5];
            #pragma unroll
            for (int q = 0; q < 5; ++q) {
                const float e  = Vv[q].x;
                const float o  = Vv[q].y;
                const float pp = e + o;
                float B = pp + dpp_sh<0x101>(pp);      // pp(l)+pp(l+1)
                float C = B + dpp_sh<0x102>(B);        // pp(l..l+3)
                Se[q] = C - dpp_sh<0x103>(o);          // cols 2l..2l+6
                So[q] = C - e;                         // cols 2l+1..2l+7
            }
            const float2 S0 = make_float2(Se[0], So[0]);
            const float2 S1 = make_float2(Se[1], So[1]);
            const float2 S2 = make_float2(Se[2], So[2]);
            const float2 S3 = make_float2(Se[3], So[3]);
            const float2 S4 = make_float2(Se[4], So[4]);

            // sum-domain SSIM (verified exact in R21: absmax 0.0)
            float2 P  = f2mul(S0, S1);
            float2 q1 = f2mul(S1, S1);
            float2 QQ = f2fma(S0, S0, q1);
            float2 N1 = f2fma(f2s(2.f), P, f2s(c1s));
            float2 D1 = f2add(QQ, f2s(c1s));
            float2 w  = f2fms(S3, 49.0f, P);           // 49*S3 - S0*S1
            float2 N2 = f2fma(f2s(k2), w, f2s(c2s));
            float2 t  = f2add(S2, S4);
            float2 u  = f2fms(t, 49.0f, QQ);           // 49*(S2+S4) - QQ
            float2 D2 = f2fma(f2s(k1), u, f2s(c2s));
            float2 num = f2mul(N1, N2);
            float2 den = f2mul(D1, D2);
            const float rdd = __builtin_amdgcn_rcpf(den.x * den.y);
            float2 s2 = make_float2(num.x * den.y * rdd,
                                    num.y * den.x * rdd);
            ls2 = f2fma(s2, vmask, ls2);
        }
    };

    static_assert(INROWS == 27 && NPAIR == 14, "ladder");

    #pragma unroll
    for (int p = 1; p < NPAIR; ++p) {
        // wait own pair-p DMAs (outstanding before: pairs p..p+2 = 6)
        if      (p <= 11) WAITV(4);
        else if (p == 12) WAITV(2);
        else              WAITV(0);
        RAWBAR();                             // all waves' pair p complete

        // read pair p into next-regs (latency hides under pair p-1 compute)
        const int sl = p & 3;
        float2 nx0 = *(const float2*)&sX[sl][0][cin];
        float2 nx1 = *(const float2*)&sX[sl][1][cin];
        float2 ny0 = *(const float2*)&sY[sl][0][cin];
        float2 ny1 = *(const float2*)&sY[sl][1][cin];

        // compute pair p-1 (lgkm-drains cur's reads from slot (p-1)&3)
        rowcompute(2 * (p - 1),     cx0, cy0);
        rowcompute(2 * (p - 1) + 1, cx1, cy1);

        // issue DMA pair p+3 into slot (p+3)&3 == (p-1)&3: its previous
        // reads were consumed just above -> race-free by program order.
        if (p + 3 < NPAIR) {
            const int q = p + 3;
            const float* s1 = (q == 13) ? gstg27 : gstg + (2 * q + 1) * IMW;
            stage16(gstg + (2 * q) * IMW, lbase + ((q & 3) * 2 + 0) * SLOTF);
            stage16(s1,                   lbase + ((q & 3) * 2 + 1) * SLOTF);
        }

        cx0 = nx0; cx1 = nx1; cy0 = ny0; cy1 = ny1;
    }

    // epilogue: pair 13 = row 26 (row 27 is clamped pad, never computed)
    rowcompute(26, cx0, cy0);

    // ---- block reduction -> plain store (reuse sX; loop fully done) ----
    float lsum = ls2.x + ls2.y;
    #pragma unroll
    for (int off = 32; off > 0; off >>= 1)
        lsum += __shfl_down(lsum, off, 64);
    __syncthreads();
    if ((tid & 63) == 0) sX[0][0][tid >> 6] = lsum;
    __syncthreads();
    if (tid == 0) {
        partials[b * NSTRIP + strip] =
            sX[0][0][0] + sX[0][0][1] + sX[0][0][2] + sX[0][0][3];
    }
}

__global__ void finalize_kernel(const float* __restrict__ partials,
                                float* __restrict__ out)
{
    float v = 0.f;
    #pragma unroll
    for (int k = 0; k < NSTRIP; ++k)
        v += partials[threadIdx.x + 64 * k];
    #pragma unroll
    for (int off = 32; off > 0; off >>= 1)
        v += __shfl_down(v, off, 64);
    if (threadIdx.x == 0)
        out[0] = 1.0f - v * (1.0f / (float)(NB * OH * OW));
}

extern "C" void kernel_launch(void* const* d_in, const int* in_sizes, int n_in,
                              void* d_out, int out_size, void* d_ws, size_t ws_size,
                              hipStream_t stream) {
    const float* X  = (const float*)d_in[0];
    const float* Y  = (const float*)d_in[1];
    const float* dr = (const float*)d_in[2];
    float* out = (float*)d_out;
    float* partials = (float*)d_ws;           // NB*NSTRIP floats, fully written

    dim3 grid(NSTRIP, NB);      // 18 x 64 = 1152 blocks
    dim3 block(BLOCK);          // 256 threads = 4 waves
    ssim_kernel<<<grid, block, 0, stream>>>(X, Y, dr, partials);
    finalize_kernel<<<1, 64, 0, stream>>>(partials, out);
}